// Round 7
// baseline (292.622 us; speedup 1.0000x reference)
//
#include <hip/hip_runtime.h>
#include <stdint.h>

#define WDIM 128
#define HID 256
#define G3 768
#define VOCAB 50257
#define EGROWS 50304          // 786 * 64
#define BATCH 4096
#define SEQ 32
#define BM 16
#define THREADS 512

// ws layout (ushort units): WiT[768][128], WhT[768][256](K-permuted), WpT[256][256](K-permuted), EG[50304][768]
#define WS_WIT 0
#define WS_WHT 98304
#define WS_WPT 294912
#define WS_WTOTAL 360448
#define WS_EG  362496ULL      // byte offset 724992

typedef __attribute__((ext_vector_type(8))) short short8;
typedef __attribute__((ext_vector_type(4))) float f32x4;

#define MFMA(a, b, c) __builtin_amdgcn_mfma_f32_16x16x32_bf16((a), (b), (c), 0, 0, 0)

__device__ __forceinline__ ushort f2bf(float f) {
    union { float f; uint32_t u; } v; v.f = f;
    uint32_t u = v.u;
    u += 0x7fffu + ((u >> 16) & 1u);   // RNE
    return (ushort)(u >> 16);
}
__device__ __forceinline__ float bf2f_lo(uint32_t p) {
    union { uint32_t u; float f; } v; v.u = p << 16; return v.f;
}
__device__ __forceinline__ float bf2f_hi(uint32_t p) {
    union { uint32_t u; float f; } v; v.u = p & 0xffff0000u; return v.f;
}
__device__ __forceinline__ float sigmoidf_(float x) {
    return __builtin_amdgcn_rcpf(1.f + __expf(-x));
}
__device__ __forceinline__ float tanhf_(float x) {
    float e2 = __expf(2.f * x);
    return 1.f - 2.f * __builtin_amdgcn_rcpf(e2 + 1.f);
}
__device__ __forceinline__ uint32_t cvtpk_bf16(float lo, float hi) {
    uint32_t pk;
    asm("v_cvt_pk_bf16_f32 %0, %1, %2" : "=v"(pk) : "v"(lo), "v"(hi));
    return pk;
}
// K-slot permutation: slot s holds original k = col_of_slot(s); pairs (c, c+16) adjacent.
__device__ __forceinline__ int col_of_slot(int s) {
    return (s & ~31) | ((s & 31) >> 1) | ((s & 1) << 4);
}

__global__ void prep_kernel(const float* __restrict__ wi, const float* __restrict__ wh,
                            const float* __restrict__ wp, ushort* __restrict__ ws) {
    int gid = blockIdx.x * blockDim.x + threadIdx.x;
    if (gid < G3 * WDIM) {
        int n = gid / WDIM, k = gid % WDIM;
        ws[WS_WIT + n * WDIM + k] = f2bf(wi[k * G3 + n]);              // unpermuted (x-path)
    } else if (gid < G3 * WDIM + G3 * HID) {
        int g = gid - G3 * WDIM;
        int n = g / HID, s = g % HID;
        ws[WS_WHT + n * HID + s] = f2bf(wh[col_of_slot(s) * G3 + n]);  // K-permuted
    } else if (gid < G3 * WDIM + G3 * HID + HID * HID) {
        int g = gid - G3 * WDIM - G3 * HID;
        int n = g / HID, s = g % HID;
        ws[WS_WPT + n * HID + s] = f2bf(wp[col_of_slot(s) * HID + n]); // K-permuted
    }
}

// ============ EG = bf16( embed @ Wi + b ) : M=50304, N=768, K=128 ============
// Pair layout along G3: dword at ushort idx m*768 + nc0+32i+2*lrow = {col nc0+32i+lrow, col +16}.
// Key fix vs R6: 16 independent B-frag loads batched into regs (asm-pinned) BEFORE the
// dependent MFMA chain -> one exposed L2 latency per 16 loads, not 16.
#define EGM 64

__global__ __launch_bounds__(256, 3) void eg_kernel(
    const float* __restrict__ embed, const float* __restrict__ bias,
    const ushort* __restrict__ WiT, ushort* __restrict__ EG)
{
    __shared__ char At[16384];            // [64 rows][256B] bf16, XOR-swizzled
    const int tid  = threadIdx.x;
    const int lane = tid & 63, wid = tid >> 6;
    const int lrow = lane & 15, kgrp = lane >> 4;
    const int m0  = blockIdx.x * EGM;

    {   // stage 64 embedding rows -> LDS bf16
        int row = tid >> 2, part = tid & 3;
        int er = m0 + row; if (er >= VOCAB) er = VOCAB - 1;
        const float* e = embed + (size_t)er * WDIM + part * 32;
        #pragma unroll
        for (int q = 0; q < 8; ++q) {
            float4 f = ((const float4*)e)[q];
            uint32_t p0 = f2bf(f.x) | ((uint32_t)f2bf(f.y) << 16);
            uint32_t p1 = f2bf(f.z) | ((uint32_t)f2bf(f.w) << 16);
            *(uint2*)(At + row * 256 + ((part * 64 + q * 8) ^ ((row & 7) << 4))) = (uint2){p0, p1};
        }
    }
    __syncthreads();

    const int arow = wid * 16 + lrow;
    short8 afr[4];
    #pragma unroll
    for (int ks = 0; ks < 4; ++ks)
        afr[ks] = *(const short8*)(At + arow * 256 + ((ks * 64 + kgrp * 16) ^ ((arow & 7) << 4)));

    for (int cb = 0; cb < 6; ++cb) {
        const int nc0 = cb * 128;
        f32x4 acc[8];
        #pragma unroll
        for (int n = 0; n < 8; ++n) acc[n] = (f32x4){0,0,0,0};

        #pragma unroll
        for (int hh = 0; hh < 2; ++hh) {
            short8 bf[16];
            #pragma unroll
            for (int q = 0; q < 16; ++q) {           // q = ks*4 + nn, n = hh*4+nn
                int colg = nc0 + (hh * 4 + (q & 3)) * 16 + lrow;
                bf[q] = *(const short8*)&WiT[(size_t)colg * WDIM + (q >> 2) * 32 + kgrp * 8];
            }
            #pragma unroll
            for (int q = 0; q < 16; ++q) asm volatile("" : "+v"(bf[q]));
            #pragma unroll
            for (int q = 0; q < 16; ++q) {
                int n = hh * 4 + (q & 3);
                acc[n] = MFMA(afr[q >> 2], bf[q], acc[n]);
            }
        }

        #pragma unroll
        for (int i = 0; i < 4; ++i) {
            float blo = bias[nc0 + 32 * i + lrow];
            float bhi = bias[nc0 + 32 * i + 16 + lrow];
            #pragma unroll
            for (int j = 0; j < 4; ++j) {
                size_t m = (size_t)(m0 + wid * 16 + kgrp * 4 + j);
                *(uint32_t*)&EG[m * G3 + nc0 + 32 * i + 2 * lrow] =
                    cvtpk_bf16(acc[2 * i][j] + blo, acc[2 * i + 1][j] + bhi);
            }
        }
    }
}

// ============ recurrent kernel: h-part only; ALL Wh in registers ============
#define R_HBF 0          // [16][512B] bf16 h, pair-slot layout, swizzled
#define R_RH  8192       // [16][512B] bf16 r*h, pair-slot layout, swizzled
#define R_TOK 16384      // [16][32] int tokens (2KB)
#define R_TOTAL 18432

extern __shared__ char smem[];

// raw barrier: flush LDS writes only; VMEM (EG prefetch) stays in flight
#define RAW_BARRIER() do {                                                    \
    asm volatile("s_waitcnt lgkmcnt(0)" ::: "memory");                        \
    __builtin_amdgcn_s_barrier();                                             \
    __builtin_amdgcn_sched_barrier(0);                                        \
} while (0)

// GC/GN: 12 dwords; [g*4+j] = pair (col ncol0+lrow | col ncol0+16+lrow) of gate g, row kgrp*4+j
#define GRU_STEP(T, GC, GN) do {                                              \
    int tn = ((T) + 1 < SEQ) ? (T) + 1 : SEQ - 1;                             \
    _Pragma("unroll")                                                         \
    for (int j = 0; j < 4; ++j) {                                             \
        int tok = tokL[(kgrp * 4 + j) * SEQ + tn];                            \
        const uint32_t* gp = EGd + (size_t)tok * 384 + gcoff;                 \
        GN[0 * 4 + j] = gp[0];                                                \
        GN[1 * 4 + j] = gp[128];                                              \
        GN[2 * 4 + j] = gp[256];                                              \
    }                                                                         \
    f32x4 az[2], ar[2];                                                       \
    _Pragma("unroll")                                                         \
    for (int j = 0; j < 4; ++j) {                                             \
        az[0][j] = bf2f_lo(GC[0 * 4 + j]);                                    \
        az[1][j] = bf2f_hi(GC[0 * 4 + j]);                                    \
        ar[0][j] = bf2f_lo(GC[1 * 4 + j]);                                    \
        ar[1][j] = bf2f_hi(GC[1 * 4 + j]);                                    \
    }                                                                         \
    _Pragma("unroll")                                                         \
    for (int ks = 0; ks < 8; ++ks) {                                          \
        short8 a = *(const short8*)(HBF + lrow * 512 + ((ks * 64 + kgrp * 16) ^ ((lrow & 7) << 4))); \
        az[0] = MFMA(a, Wz[ks][0], az[0]);                                    \
        az[1] = MFMA(a, Wz[ks][1], az[1]);                                    \
        ar[0] = MFMA(a, Wr[ks][0], ar[0]);                                    \
        ar[1] = MFMA(a, Wr[ks][1], ar[1]);                                    \
    }                                                                         \
    _Pragma("unroll")                                                         \
    for (int j = 0; j < 4; ++j) {                                             \
        int row = kgrp * 4 + j;                                               \
        float z0 = sigmoidf_(az[0][j]); az[0][j] = z0;                        \
        float z1 = sigmoidf_(az[1][j]); az[1][j] = z1;                        \
        float r0 = sigmoidf_(ar[0][j]) * h[0][j];                             \
        float r1 = sigmoidf_(ar[1][j]) * h[1][j];                             \
        *(uint32_t*)(RH + row * 512 + ((wid * 64 + lrow * 4) ^ ((row & 7) << 4))) = cvtpk_bf16(r0, r1); \
    }                                                                         \
    RAW_BARRIER();                                                            \
    f32x4 aa[2];                                                              \
    _Pragma("unroll")                                                         \
    for (int j = 0; j < 4; ++j) {                                             \
        aa[0][j] = bf2f_lo(GC[2 * 4 + j]);                                    \
        aa[1][j] = bf2f_hi(GC[2 * 4 + j]);                                    \
    }                                                                         \
    _Pragma("unroll")                                                         \
    for (int ks = 0; ks < 8; ++ks) {                                          \
        short8 a = *(const short8*)(RH + lrow * 512 + ((ks * 64 + kgrp * 16) ^ ((lrow & 7) << 4))); \
        aa[0] = MFMA(a, Wa[ks][0], aa[0]);                                    \
        aa[1] = MFMA(a, Wa[ks][1], aa[1]);                                    \
    }                                                                         \
    _Pragma("unroll")                                                         \
    for (int j = 0; j < 4; ++j) {                                             \
        int row = kgrp * 4 + j;                                               \
        float a0 = tanhf_(aa[0][j]);                                          \
        float a1 = tanhf_(aa[1][j]);                                          \
        float h0 = (1.f - az[0][j]) * h[0][j] + az[0][j] * a0;                \
        float h1 = (1.f - az[1][j]) * h[1][j] + az[1][j] * a1;                \
        h[0][j] = h0; h[1][j] = h1;                                           \
        *(uint32_t*)(HBF + row * 512 + ((wid * 64 + lrow * 4) ^ ((row & 7) << 4))) = cvtpk_bf16(h0, h1); \
    }                                                                         \
    RAW_BARRIER();                                                            \
} while (0)

__global__ __launch_bounds__(THREADS, 2) void gru_rec(
    const int* __restrict__ x, const ushort* __restrict__ EG,
    const float* __restrict__ bp, const ushort* __restrict__ WhT,
    const ushort* __restrict__ WpT, float* __restrict__ out)
{
    char* HBF = smem + R_HBF;
    char* RH  = smem + R_RH;
    int*  tokL = (int*)(smem + R_TOK);

    const int tid  = threadIdx.x;
    const int lane = tid & 63;
    const int wid  = tid >> 6;
    const int lrow = lane & 15;
    const int kgrp = lane >> 4;
    const int r0   = blockIdx.x * BM;
    const int ncol0 = wid * 32;
    const uint32_t* EGd = (const uint32_t*)EG;
    const int gcoff = (ncol0 >> 1) + lrow;     // dword offset within EG row

    *(short8*)(HBF + tid * 16) = (short8){0,0,0,0,0,0,0,0};
    tokL[tid] = x[r0 * SEQ + tid];       // 16 rows x 32 steps

    // resident Wh z/r/a fragments (K-permuted), pinned against rematerialization
    short8 Wz[8][2], Wr[8][2], Wa[8][2];
    #pragma unroll
    for (int ks = 0; ks < 8; ++ks)
        #pragma unroll
        for (int n = 0; n < 2; ++n) {
            int colg = ncol0 + n * 16 + lrow;
            Wz[ks][n] = *(const short8*)&WhT[(size_t)colg * HID + ks * 32 + kgrp * 8];
            Wr[ks][n] = *(const short8*)&WhT[(size_t)(HID + colg) * HID + ks * 32 + kgrp * 8];
            Wa[ks][n] = *(const short8*)&WhT[(size_t)(2 * HID + colg) * HID + ks * 32 + kgrp * 8];
            asm volatile("" : "+v"(Wz[ks][n]), "+v"(Wr[ks][n]), "+v"(Wa[ks][n]));
        }

    float bpr[2];
    #pragma unroll
    for (int n = 0; n < 2; ++n) bpr[n] = bp[ncol0 + n * 16 + lrow];

    float h[2][4] = {{0.f,0.f,0.f,0.f},{0.f,0.f,0.f,0.f}};

    __syncthreads();

    // prologue: gather EG pairs for t=0
    uint32_t gxA[12], gxB[12];
    #pragma unroll
    for (int j = 0; j < 4; ++j) {
        int tok = tokL[(kgrp * 4 + j) * SEQ + 0];
        const uint32_t* gp = EGd + (size_t)tok * 384 + gcoff;
        gxA[0 * 4 + j] = gp[0];
        gxA[1 * 4 + j] = gp[128];
        gxA[2 * 4 + j] = gp[256];
    }

    for (int t = 0; t < SEQ; t += 2) {
        GRU_STEP(t,     gxA, gxB);
        GRU_STEP(t + 1, gxB, gxA);
    }

    // ---- projection: out = h @ w_p + b_p (WpT K-permuted to match HBF slots) ----
    f32x4 ap[2] = {{0,0,0,0},{0,0,0,0}};
    #pragma unroll
    for (int ks = 0; ks < 8; ++ks) {
        short8 a = *(const short8*)(HBF + lrow * 512 + ((ks * 64 + kgrp * 16) ^ ((lrow & 7) << 4)));
        #pragma unroll
        for (int n = 0; n < 2; ++n) {
            int colg = ncol0 + n * 16 + lrow;
            short8 bw = *(const short8*)&WpT[(size_t)colg * HID + ks * 32 + kgrp * 8];
            ap[n] = MFMA(a, bw, ap[n]);
        }
    }
    #pragma unroll
    for (int n = 0; n < 2; ++n) {
        int colg = ncol0 + n * 16 + lrow;
        #pragma unroll
        for (int j = 0; j < 4; ++j) {
            int row = kgrp * 4 + j;
            out[(size_t)(r0 + row) * HID + colg] = ap[n][j] + bpr[n];
        }
    }
}

extern "C" void kernel_launch(void* const* d_in, const int* in_sizes, int n_in,
                              void* d_out, int out_size, void* d_ws, size_t ws_size,
                              hipStream_t stream) {
    const int*   x     = (const int*)d_in[0];
    const float* embed = (const float*)d_in[1];
    const float* wi    = (const float*)d_in[2];
    const float* wh    = (const float*)d_in[3];
    const float* b     = (const float*)d_in[4];
    const float* wp    = (const float*)d_in[5];
    const float* bp    = (const float*)d_in[6];
    float* out = (float*)d_out;
    ushort* ws = (ushort*)d_ws;

    (void)hipFuncSetAttribute((const void*)gru_rec,
                              hipFuncAttributeMaxDynamicSharedMemorySize, R_TOTAL);

    hipLaunchKernelGGL(prep_kernel, dim3((WS_WTOTAL + 255) / 256), dim3(256), 0, stream,
                       wi, wh, wp, ws);

    ushort* eg = ws + WS_EG;
    hipLaunchKernelGGL(eg_kernel, dim3(EGROWS / EGM), dim3(256), 0, stream,
                       embed, b, ws + WS_WIT, eg);
    hipLaunchKernelGGL(gru_rec, dim3(BATCH / BM), dim3(THREADS), R_TOTAL, stream,
                       x, eg, bp, ws + WS_WHT, ws + WS_WPT, out);
}

// Round 8
// 130.343 us; speedup vs baseline: 2.2450x; 2.2450x over previous
//
#include <hip/hip_runtime.h>
#include <stdint.h>

#define WDIM 128
#define HID 256
#define G3 768
#define VOCAB 50257
#define EGROWS 50304          // 393 * 128
#define BATCH 4096
#define SEQ 32
#define BM 16
#define THREADS 512

// ws layout (ushort units): WiT[768][128], WhT[768][256](K-permuted), WpT[256][256](K-permuted), EG[50304][768]
#define WS_WIT 0
#define WS_WHT 98304
#define WS_WPT 294912
#define WS_WTOTAL 360448
#define WS_EG  362496ULL      // byte offset 724992

typedef __attribute__((ext_vector_type(8))) short short8;
typedef __attribute__((ext_vector_type(4))) float f32x4;

#define MFMA(a, b, c) __builtin_amdgcn_mfma_f32_16x16x32_bf16((a), (b), (c), 0, 0, 0)

__device__ __forceinline__ ushort f2bf(float f) {
    union { float f; uint32_t u; } v; v.f = f;
    uint32_t u = v.u;
    u += 0x7fffu + ((u >> 16) & 1u);   // RNE
    return (ushort)(u >> 16);
}
__device__ __forceinline__ float bf2f_lo(uint32_t p) {
    union { uint32_t u; float f; } v; v.u = p << 16; return v.f;
}
__device__ __forceinline__ float bf2f_hi(uint32_t p) {
    union { uint32_t u; float f; } v; v.u = p & 0xffff0000u; return v.f;
}
__device__ __forceinline__ float sigmoidf_(float x) {
    return __builtin_amdgcn_rcpf(1.f + __expf(-x));
}
__device__ __forceinline__ float tanhf_(float x) {
    float e2 = __expf(2.f * x);
    return 1.f - 2.f * __builtin_amdgcn_rcpf(e2 + 1.f);
}
__device__ __forceinline__ uint32_t cvtpk_bf16(float lo, float hi) {
    uint32_t pk;
    asm("v_cvt_pk_bf16_f32 %0, %1, %2" : "=v"(pk) : "v"(lo), "v"(hi));
    return pk;
}
// K-slot permutation: slot s holds original k = col_of_slot(s); pairs (c, c+16) adjacent.
__device__ __forceinline__ int col_of_slot(int s) {
    return (s & ~31) | ((s & 31) >> 1) | ((s & 1) << 4);
}

__global__ void prep_kernel(const float* __restrict__ wi, const float* __restrict__ wh,
                            const float* __restrict__ wp, ushort* __restrict__ ws) {
    int gid = blockIdx.x * blockDim.x + threadIdx.x;
    if (gid < G3 * WDIM) {
        int n = gid / WDIM, k = gid % WDIM;
        ws[WS_WIT + n * WDIM + k] = f2bf(wi[k * G3 + n]);              // unpermuted (x-path)
    } else if (gid < G3 * WDIM + G3 * HID) {
        int g = gid - G3 * WDIM;
        int n = g / HID, s = g % HID;
        ws[WS_WHT + n * HID + s] = f2bf(wh[col_of_slot(s) * G3 + n]);  // K-permuted
    } else if (gid < G3 * WDIM + G3 * HID + HID * HID) {
        int g = gid - G3 * WDIM - G3 * HID;
        int n = g / HID, s = g % HID;
        ws[WS_WPT + n * HID + s] = f2bf(wp[col_of_slot(s) * HID + n]); // K-permuted
    }
}

// ============ EG = bf16( embed @ Wi + b ) : M=50304, N=768, K=128 ============
// B-RESIDENT design: 8 waves/block, wave w owns 96 cols -> its whole B slice
// (24 short8 = 96 VGPR) loaded ONCE per block and pinned. Block = 128-row
// M-tile; A staged once in LDS; 8 row-tiles x 24 MFMA per wave.
// B L2 traffic: 393 blocks x 192KB = 75 MB (was 604 MB).
#define EGM 128

__global__ __launch_bounds__(512, 2) void eg_kernel(
    const float* __restrict__ embed, const float* __restrict__ bias,
    const ushort* __restrict__ WiT, ushort* __restrict__ EG)
{
    __shared__ char At[32768];            // [128 rows][256B] bf16, XOR-swizzled
    const int tid  = threadIdx.x;
    const int lane = tid & 63, wid = tid >> 6;     // 8 waves
    const int lrow = lane & 15, kgrp = lane >> 4;
    const int m0  = blockIdx.x * EGM;
    const int c0  = wid * 96;                      // wave's col base

    {   // stage 128 embedding rows -> LDS bf16 (4 threads/row, 32 floats each)
        int row = tid >> 2, part = tid & 3;
        int er = m0 + row; if (er >= VOCAB) er = VOCAB - 1;
        const float* e = embed + (size_t)er * WDIM + part * 32;
        #pragma unroll
        for (int q = 0; q < 8; ++q) {
            float4 f = ((const float4*)e)[q];
            uint32_t p0 = f2bf(f.x) | ((uint32_t)f2bf(f.y) << 16);
            uint32_t p1 = f2bf(f.z) | ((uint32_t)f2bf(f.w) << 16);
            *(uint2*)(At + row * 256 + ((part * 64 + q * 8) ^ ((row & 7) << 4))) = (uint2){p0, p1};
        }
    }

    // B preload: 24 fragments, resident for the whole block
    short8 Bw[6][4];
    #pragma unroll
    for (int n = 0; n < 6; ++n)
        #pragma unroll
        for (int ks = 0; ks < 4; ++ks) {
            Bw[n][ks] = *(const short8*)&WiT[(size_t)(c0 + n * 16 + lrow) * WDIM + ks * 32 + kgrp * 8];
            asm volatile("" : "+v"(Bw[n][ks]));
        }

    float bv[6];
    #pragma unroll
    for (int n = 0; n < 6; ++n) bv[n] = bias[c0 + n * 16 + lrow];

    __syncthreads();

    #pragma unroll
    for (int rt = 0; rt < 8; ++rt) {
        const int arow = rt * 16 + lrow;
        short8 afr[4];
        #pragma unroll
        for (int ks = 0; ks < 4; ++ks)
            afr[ks] = *(const short8*)(At + arow * 256 + ((ks * 64 + kgrp * 16) ^ ((arow & 7) << 4)));

        f32x4 acc[6];
        #pragma unroll
        for (int n = 0; n < 6; ++n) acc[n] = (f32x4){0,0,0,0};
        #pragma unroll
        for (int ks = 0; ks < 4; ++ks)
            #pragma unroll
            for (int n = 0; n < 6; ++n)
                acc[n] = MFMA(afr[ks], Bw[n][ks], acc[n]);

        // pair-dword stores: cols (c0+32i+lrow, +16); 64B contiguous per 16 lanes
        #pragma unroll
        for (int i = 0; i < 3; ++i)
            #pragma unroll
            for (int j = 0; j < 4; ++j) {
                size_t m = (size_t)(m0 + rt * 16 + kgrp * 4 + j);
                *(uint32_t*)&EG[m * G3 + c0 + 32 * i + 2 * lrow] =
                    cvtpk_bf16(acc[2 * i][j] + bv[2 * i], acc[2 * i + 1][j] + bv[2 * i + 1]);
            }
    }
}

// ============ recurrent kernel (R6 config: Wz/Wr regs, Wh_a LDS) + setprio ============
#define R_WHA 0          // Wh_a (K-permuted rows) swizzled [256 cols][512B]  (128KB)
#define R_HBF 131072     // [16][512B] bf16 h, pair-slot layout, swizzled
#define R_RH  139264     // [16][512B] bf16 r*h, pair-slot layout, swizzled
#define R_TOK 147456     // [16][32] int tokens (2KB)
#define R_TOTAL 149504

extern __shared__ char smem[];

// raw barrier: flush LDS writes only; VMEM (EG prefetch) stays in flight
#define RAW_BARRIER() do {                                                    \
    asm volatile("s_waitcnt lgkmcnt(0)" ::: "memory");                        \
    __builtin_amdgcn_s_barrier();                                             \
    __builtin_amdgcn_sched_barrier(0);                                        \
} while (0)

// GC/GN: 12 dwords; [g*4+j] = pair (col ncol0+lrow | col ncol0+16+lrow) of gate g, row kgrp*4+j
#define GRU_STEP(T, GC, GN) do {                                              \
    int tn = ((T) + 1 < SEQ) ? (T) + 1 : SEQ - 1;                             \
    _Pragma("unroll")                                                         \
    for (int j = 0; j < 4; ++j) {                                             \
        int tok = tokL[(kgrp * 4 + j) * SEQ + tn];                            \
        const uint32_t* gp = EGd + (size_t)tok * 384 + gcoff;                 \
        GN[0 * 4 + j] = gp[0];                                                \
        GN[1 * 4 + j] = gp[128];                                              \
        GN[2 * 4 + j] = gp[256];                                              \
    }                                                                         \
    f32x4 az[2], ar[2];                                                       \
    _Pragma("unroll")                                                         \
    for (int j = 0; j < 4; ++j) {                                             \
        az[0][j] = bf2f_lo(GC[0 * 4 + j]);                                    \
        az[1][j] = bf2f_hi(GC[0 * 4 + j]);                                    \
        ar[0][j] = bf2f_lo(GC[1 * 4 + j]);                                    \
        ar[1][j] = bf2f_hi(GC[1 * 4 + j]);                                    \
    }                                                                         \
    __builtin_amdgcn_s_setprio(1);                                            \
    _Pragma("unroll")                                                         \
    for (int ks = 0; ks < 8; ++ks) {                                          \
        short8 a = *(const short8*)(HBF + lrow * 512 + ((ks * 64 + kgrp * 16) ^ ((lrow & 7) << 4))); \
        az[0] = MFMA(a, Wz[ks][0], az[0]);                                    \
        az[1] = MFMA(a, Wz[ks][1], az[1]);                                    \
        ar[0] = MFMA(a, Wr[ks][0], ar[0]);                                    \
        ar[1] = MFMA(a, Wr[ks][1], ar[1]);                                    \
    }                                                                         \
    __builtin_amdgcn_s_setprio(0);                                            \
    _Pragma("unroll")                                                         \
    for (int j = 0; j < 4; ++j) {                                             \
        int row = kgrp * 4 + j;                                               \
        float z0 = sigmoidf_(az[0][j]); az[0][j] = z0;                        \
        float z1 = sigmoidf_(az[1][j]); az[1][j] = z1;                        \
        float r0 = sigmoidf_(ar[0][j]) * h[0][j];                             \
        float r1 = sigmoidf_(ar[1][j]) * h[1][j];                             \
        *(uint32_t*)(RH + row * 512 + ((wid * 64 + lrow * 4) ^ ((row & 7) << 4))) = cvtpk_bf16(r0, r1); \
    }                                                                         \
    RAW_BARRIER();                                                            \
    f32x4 aa[2];                                                              \
    _Pragma("unroll")                                                         \
    for (int j = 0; j < 4; ++j) {                                             \
        aa[0][j] = bf2f_lo(GC[2 * 4 + j]);                                    \
        aa[1][j] = bf2f_hi(GC[2 * 4 + j]);                                    \
    }                                                                         \
    __builtin_amdgcn_s_setprio(1);                                            \
    _Pragma("unroll")                                                         \
    for (int ks = 0; ks < 8; ++ks) {                                          \
        short8 a = *(const short8*)(RH + lrow * 512 + ((ks * 64 + kgrp * 16) ^ ((lrow & 7) << 4))); \
        _Pragma("unroll")                                                     \
        for (int n = 0; n < 2; ++n) {                                         \
            int colg = ncol0 + n * 16 + lrow;                                 \
            short8 bw = *(const short8*)(WhA + colg * 512 + ((ks * 64 + kgrp * 16) ^ ((colg & 7) << 4))); \
            aa[n] = MFMA(a, bw, aa[n]);                                       \
        }                                                                     \
    }                                                                         \
    __builtin_amdgcn_s_setprio(0);                                            \
    _Pragma("unroll")                                                         \
    for (int j = 0; j < 4; ++j) {                                             \
        int row = kgrp * 4 + j;                                               \
        float a0 = tanhf_(aa[0][j]);                                          \
        float a1 = tanhf_(aa[1][j]);                                          \
        float h0 = (1.f - az[0][j]) * h[0][j] + az[0][j] * a0;                \
        float h1 = (1.f - az[1][j]) * h[1][j] + az[1][j] * a1;                \
        h[0][j] = h0; h[1][j] = h1;                                           \
        *(uint32_t*)(HBF + row * 512 + ((wid * 64 + lrow * 4) ^ ((row & 7) << 4))) = cvtpk_bf16(h0, h1); \
    }                                                                         \
    RAW_BARRIER();                                                            \
} while (0)

__global__ __launch_bounds__(THREADS, 2) void gru_rec(
    const int* __restrict__ x, const ushort* __restrict__ EG,
    const float* __restrict__ bp, const ushort* __restrict__ WhT,
    const ushort* __restrict__ WpT, float* __restrict__ out)
{
    char* WhA = smem + R_WHA;
    char* HBF = smem + R_HBF;
    char* RH  = smem + R_RH;
    int*  tokL = (int*)(smem + R_TOK);

    const int tid  = threadIdx.x;
    const int lane = tid & 63;
    const int wid  = tid >> 6;
    const int lrow = lane & 15;
    const int kgrp = lane >> 4;
    const int r0   = blockIdx.x * BM;
    const int ncol0 = wid * 32;
    const uint32_t* EGd = (const uint32_t*)EG;
    const int gcoff = (ncol0 >> 1) + lrow;     // dword offset within EG row

    // one-time LDS fill: Wh_a (rows K-permuted already), swizzled
    for (int c = tid; c < 8192; c += THREADS) {
        int row = c >> 5, ch = c & 31;
        short8 v = *(const short8*)&WhT[(size_t)(2 * HID + row) * HID + ch * 8];
        *(short8*)(WhA + row * 512 + ((ch * 16) ^ ((row & 7) << 4))) = v;
    }
    *(short8*)(HBF + tid * 16) = (short8){0,0,0,0,0,0,0,0};
    tokL[tid] = x[r0 * SEQ + tid];       // 16 rows x 32 steps

    // resident Wh z/r fragments (K-permuted), pinned against rematerialization
    short8 Wz[8][2], Wr[8][2];
    #pragma unroll
    for (int ks = 0; ks < 8; ++ks)
        #pragma unroll
        for (int n = 0; n < 2; ++n) {
            int colg = ncol0 + n * 16 + lrow;
            Wz[ks][n] = *(const short8*)&WhT[(size_t)colg * HID + ks * 32 + kgrp * 8];
            Wr[ks][n] = *(const short8*)&WhT[(size_t)(HID + colg) * HID + ks * 32 + kgrp * 8];
            asm volatile("" : "+v"(Wz[ks][n]), "+v"(Wr[ks][n]));
        }

    float bpr[2];
    #pragma unroll
    for (int n = 0; n < 2; ++n) bpr[n] = bp[ncol0 + n * 16 + lrow];

    float h[2][4] = {{0.f,0.f,0.f,0.f},{0.f,0.f,0.f,0.f}};

    __syncthreads();

    // prologue: gather EG pairs for t=0
    uint32_t gxA[12], gxB[12];
    #pragma unroll
    for (int j = 0; j < 4; ++j) {
        int tok = tokL[(kgrp * 4 + j) * SEQ + 0];
        const uint32_t* gp = EGd + (size_t)tok * 384 + gcoff;
        gxA[0 * 4 + j] = gp[0];
        gxA[1 * 4 + j] = gp[128];
        gxA[2 * 4 + j] = gp[256];
    }

    for (int t = 0; t < SEQ; t += 2) {
        GRU_STEP(t,     gxA, gxB);
        GRU_STEP(t + 1, gxB, gxA);
    }

    // ---- projection: out = h @ w_p + b_p (WpT K-permuted to match HBF slots) ----
    f32x4 ap[2] = {{0,0,0,0},{0,0,0,0}};
    #pragma unroll
    for (int ks = 0; ks < 8; ++ks) {
        short8 a = *(const short8*)(HBF + lrow * 512 + ((ks * 64 + kgrp * 16) ^ ((lrow & 7) << 4)));
        #pragma unroll
        for (int n = 0; n < 2; ++n) {
            int colg = ncol0 + n * 16 + lrow;
            short8 bw = *(const short8*)&WpT[(size_t)colg * HID + ks * 32 + kgrp * 8];
            ap[n] = MFMA(a, bw, ap[n]);
        }
    }
    #pragma unroll
    for (int n = 0; n < 2; ++n) {
        int colg = ncol0 + n * 16 + lrow;
        #pragma unroll
        for (int j = 0; j < 4; ++j) {
            int row = kgrp * 4 + j;
            out[(size_t)(r0 + row) * HID + colg] = ap[n][j] + bpr[n];
        }
    }
}

extern "C" void kernel_launch(void* const* d_in, const int* in_sizes, int n_in,
                              void* d_out, int out_size, void* d_ws, size_t ws_size,
                              hipStream_t stream) {
    const int*   x     = (const int*)d_in[0];
    const float* embed = (const float*)d_in[1];
    const float* wi    = (const float*)d_in[2];
    const float* wh    = (const float*)d_in[3];
    const float* b     = (const float*)d_in[4];
    const float* wp    = (const float*)d_in[5];
    const float* bp    = (const float*)d_in[6];
    float* out = (float*)d_out;
    ushort* ws = (ushort*)d_ws;

    (void)hipFuncSetAttribute((const void*)gru_rec,
                              hipFuncAttributeMaxDynamicSharedMemorySize, R_TOTAL);

    hipLaunchKernelGGL(prep_kernel, dim3((WS_WTOTAL + 255) / 256), dim3(256), 0, stream,
                       wi, wh, wp, ws);

    ushort* eg = ws + WS_EG;
    hipLaunchKernelGGL(eg_kernel, dim3(EGROWS / EGM), dim3(512), 0, stream,
                       embed, b, ws + WS_WIT, eg);
    hipLaunchKernelGGL(gru_rec, dim3(BATCH / BM), dim3(THREADS), R_TOTAL, stream,
                       x, eg, bp, ws + WS_WHT, ws + WS_WPT, out);
}

// Round 9
// 125.339 us; speedup vs baseline: 2.3346x; 1.0399x over previous
//
#include <hip/hip_runtime.h>
#include <stdint.h>

#define WDIM 128
#define HID 256
#define G3 768
#define VOCAB 50257
#define EGROWS 50304          // 393 * 128
#define BATCH 4096
#define SEQ 32
#define BM 16
#define THREADS 512

// ws layout (ushort units): WiT[768][128], WhT[768][256](K-permuted), WpT[256][256](K-permuted), EG[50304][768]
#define WS_WIT 0
#define WS_WHT 98304
#define WS_WPT 294912
#define WS_WTOTAL 360448
#define WS_EG  362496ULL      // byte offset 724992

typedef __attribute__((ext_vector_type(8))) short short8;
typedef __attribute__((ext_vector_type(4))) float f32x4;

#define MFMA(a, b, c) __builtin_amdgcn_mfma_f32_16x16x32_bf16((a), (b), (c), 0, 0, 0)

__device__ __forceinline__ ushort f2bf(float f) {
    union { float f; uint32_t u; } v; v.f = f;
    uint32_t u = v.u;
    u += 0x7fffu + ((u >> 16) & 1u);   // RNE
    return (ushort)(u >> 16);
}
__device__ __forceinline__ float bf2f_lo(uint32_t p) {
    union { uint32_t u; float f; } v; v.u = p << 16; return v.f;
}
__device__ __forceinline__ float bf2f_hi(uint32_t p) {
    union { uint32_t u; float f; } v; v.u = p & 0xffff0000u; return v.f;
}
__device__ __forceinline__ float sigmoidf_(float x) {
    return __builtin_amdgcn_rcpf(1.f + __expf(-x));
}
__device__ __forceinline__ float tanhf_(float x) {
    float e2 = __expf(2.f * x);
    return 1.f - 2.f * __builtin_amdgcn_rcpf(e2 + 1.f);
}
__device__ __forceinline__ uint32_t cvtpk_bf16(float lo, float hi) {
    uint32_t pk;
    asm("v_cvt_pk_bf16_f32 %0, %1, %2" : "=v"(pk) : "v"(lo), "v"(hi));
    return pk;
}
// K-slot permutation: slot s holds original k = col_of_slot(s); pairs (c, c+16) adjacent.
__device__ __forceinline__ int col_of_slot(int s) {
    return (s & ~31) | ((s & 31) >> 1) | ((s & 1) << 4);
}

__global__ void prep_kernel(const float* __restrict__ wi, const float* __restrict__ wh,
                            const float* __restrict__ wp, ushort* __restrict__ ws) {
    int gid = blockIdx.x * blockDim.x + threadIdx.x;
    if (gid < G3 * WDIM) {
        int n = gid / WDIM, k = gid % WDIM;
        ws[WS_WIT + n * WDIM + k] = f2bf(wi[k * G3 + n]);              // unpermuted (x-path)
    } else if (gid < G3 * WDIM + G3 * HID) {
        int g = gid - G3 * WDIM;
        int n = g / HID, s = g % HID;
        ws[WS_WHT + n * HID + s] = f2bf(wh[col_of_slot(s) * G3 + n]);  // K-permuted
    } else if (gid < G3 * WDIM + G3 * HID + HID * HID) {
        int g = gid - G3 * WDIM - G3 * HID;
        int n = g / HID, s = g % HID;
        ws[WS_WPT + n * HID + s] = f2bf(wp[col_of_slot(s) * HID + n]); // K-permuted
    }
}

// ============ EG = bf16( embed @ Wi + b ) : M=50304, N=768, K=128 ============
// B-RESIDENT: 8 waves/block, wave w owns 96 cols (24 short8 = 96 VGPR, pinned).
// Block = 128-row M-tile; A staged once in LDS; 8 row-tiles x 24 MFMA per wave.
#define EGM 128

__global__ __launch_bounds__(512, 2) void eg_kernel(
    const float* __restrict__ embed, const float* __restrict__ bias,
    const ushort* __restrict__ WiT, ushort* __restrict__ EG)
{
    __shared__ char At[32768];            // [128 rows][256B] bf16, XOR-swizzled
    const int tid  = threadIdx.x;
    const int lane = tid & 63, wid = tid >> 6;     // 8 waves
    const int lrow = lane & 15, kgrp = lane >> 4;
    const int m0  = blockIdx.x * EGM;
    const int c0  = wid * 96;                      // wave's col base

    {   // stage 128 embedding rows -> LDS bf16 (4 threads/row, 32 floats each)
        int row = tid >> 2, part = tid & 3;
        int er = m0 + row; if (er >= VOCAB) er = VOCAB - 1;
        const float* e = embed + (size_t)er * WDIM + part * 32;
        #pragma unroll
        for (int q = 0; q < 8; ++q) {
            float4 f = ((const float4*)e)[q];
            uint32_t p0 = f2bf(f.x) | ((uint32_t)f2bf(f.y) << 16);
            uint32_t p1 = f2bf(f.z) | ((uint32_t)f2bf(f.w) << 16);
            *(uint2*)(At + row * 256 + ((part * 64 + q * 8) ^ ((row & 7) << 4))) = (uint2){p0, p1};
        }
    }

    // B preload: 24 fragments, resident for the whole block
    short8 Bw[6][4];
    #pragma unroll
    for (int n = 0; n < 6; ++n)
        #pragma unroll
        for (int ks = 0; ks < 4; ++ks) {
            Bw[n][ks] = *(const short8*)&WiT[(size_t)(c0 + n * 16 + lrow) * WDIM + ks * 32 + kgrp * 8];
            asm volatile("" : "+v"(Bw[n][ks]));
        }

    float bv[6];
    #pragma unroll
    for (int n = 0; n < 6; ++n) bv[n] = bias[c0 + n * 16 + lrow];

    __syncthreads();

    #pragma unroll
    for (int rt = 0; rt < 8; ++rt) {
        const int arow = rt * 16 + lrow;
        short8 afr[4];
        #pragma unroll
        for (int ks = 0; ks < 4; ++ks)
            afr[ks] = *(const short8*)(At + arow * 256 + ((ks * 64 + kgrp * 16) ^ ((arow & 7) << 4)));

        f32x4 acc[6];
        #pragma unroll
        for (int n = 0; n < 6; ++n) acc[n] = (f32x4){0,0,0,0};
        #pragma unroll
        for (int ks = 0; ks < 4; ++ks)
            #pragma unroll
            for (int n = 0; n < 6; ++n)
                acc[n] = MFMA(afr[ks], Bw[n][ks], acc[n]);

        // pair-dword stores: cols (c0+32i+lrow, +16); 64B contiguous per 16 lanes
        #pragma unroll
        for (int i = 0; i < 3; ++i)
            #pragma unroll
            for (int j = 0; j < 4; ++j) {
                size_t m = (size_t)(m0 + rt * 16 + kgrp * 4 + j);
                *(uint32_t*)&EG[m * G3 + c0 + 32 * i + 2 * lrow] =
                    cvtpk_bf16(acc[2 * i][j] + bv[2 * i], acc[2 * i + 1][j] + bv[2 * i + 1]);
            }
    }
}

// ============ recurrent kernel (R6 structure: Wz/Wr regs, Wh_a LDS, NO setprio) ============
#define R_WHA 0          // Wh_a (K-permuted rows) swizzled [256 cols][512B]  (128KB)
#define R_HBF 131072     // [16][512B] bf16 h, pair-slot layout, swizzled
#define R_RH  139264     // [16][512B] bf16 r*h, pair-slot layout, swizzled
#define R_TOK 147456     // [16][32] int tokens (2KB)
#define R_TOTAL 149504

extern __shared__ char smem[];

// raw barrier: flush LDS writes only; VMEM (EG prefetch) stays in flight
#define RAW_BARRIER() do {                                                    \
    asm volatile("s_waitcnt lgkmcnt(0)" ::: "memory");                        \
    __builtin_amdgcn_s_barrier();                                             \
    __builtin_amdgcn_sched_barrier(0);                                        \
} while (0)

// GC/GN: 12 dwords; [g*4+j] = pair (col ncol0+lrow | col ncol0+16+lrow) of gate g, row kgrp*4+j
#define GRU_STEP(T, GC, GN) do {                                              \
    int tn = ((T) + 1 < SEQ) ? (T) + 1 : SEQ - 1;                             \
    _Pragma("unroll")                                                         \
    for (int j = 0; j < 4; ++j) {                                             \
        int tok = tokL[(kgrp * 4 + j) * SEQ + tn];                            \
        const uint32_t* gp = EGd + (size_t)tok * 384 + gcoff;                 \
        GN[0 * 4 + j] = gp[0];                                                \
        GN[1 * 4 + j] = gp[128];                                              \
        GN[2 * 4 + j] = gp[256];                                              \
    }                                                                         \
    f32x4 az[2], ar[2];                                                       \
    _Pragma("unroll")                                                         \
    for (int j = 0; j < 4; ++j) {                                             \
        az[0][j] = bf2f_lo(GC[0 * 4 + j]);                                    \
        az[1][j] = bf2f_hi(GC[0 * 4 + j]);                                    \
        ar[0][j] = bf2f_lo(GC[1 * 4 + j]);                                    \
        ar[1][j] = bf2f_hi(GC[1 * 4 + j]);                                    \
    }                                                                         \
    _Pragma("unroll")                                                         \
    for (int ks = 0; ks < 8; ++ks) {                                          \
        short8 a = *(const short8*)(HBF + lrow * 512 + ((ks * 64 + kgrp * 16) ^ ((lrow & 7) << 4))); \
        az[0] = MFMA(a, Wz[ks][0], az[0]);                                    \
        az[1] = MFMA(a, Wz[ks][1], az[1]);                                    \
        ar[0] = MFMA(a, Wr[ks][0], ar[0]);                                    \
        ar[1] = MFMA(a, Wr[ks][1], ar[1]);                                    \
    }                                                                         \
    _Pragma("unroll")                                                         \
    for (int j = 0; j < 4; ++j) {                                             \
        int row = kgrp * 4 + j;                                               \
        float z0 = sigmoidf_(az[0][j]); az[0][j] = z0;                        \
        float z1 = sigmoidf_(az[1][j]); az[1][j] = z1;                        \
        float r0 = sigmoidf_(ar[0][j]) * h[0][j];                             \
        float r1 = sigmoidf_(ar[1][j]) * h[1][j];                             \
        *(uint32_t*)(RH + row * 512 + ((wid * 64 + lrow * 4) ^ ((row & 7) << 4))) = cvtpk_bf16(r0, r1); \
    }                                                                         \
    RAW_BARRIER();                                                            \
    /* a-GEMM: 4 independent chains (2 cols x K-low/K-high) to cut MFMA latency exposure */ \
    f32x4 aaL[2], aaH[2];                                                     \
    _Pragma("unroll")                                                         \
    for (int j = 0; j < 4; ++j) {                                             \
        aaL[0][j] = bf2f_lo(GC[2 * 4 + j]);                                   \
        aaL[1][j] = bf2f_hi(GC[2 * 4 + j]);                                   \
        aaH[0][j] = 0.f; aaH[1][j] = 0.f;                                     \
    }                                                                         \
    _Pragma("unroll")                                                         \
    for (int ks = 0; ks < 4; ++ks) {                                          \
        short8 aL = *(const short8*)(RH + lrow * 512 + ((ks * 64 + kgrp * 16) ^ ((lrow & 7) << 4))); \
        short8 aH = *(const short8*)(RH + lrow * 512 + (((ks + 4) * 64 + kgrp * 16) ^ ((lrow & 7) << 4))); \
        _Pragma("unroll")                                                     \
        for (int n = 0; n < 2; ++n) {                                         \
            int colg = ncol0 + n * 16 + lrow;                                 \
            short8 bwL = *(const short8*)(WhA + colg * 512 + ((ks * 64 + kgrp * 16) ^ ((colg & 7) << 4))); \
            short8 bwH = *(const short8*)(WhA + colg * 512 + (((ks + 4) * 64 + kgrp * 16) ^ ((colg & 7) << 4))); \
            aaL[n] = MFMA(aL, bwL, aaL[n]);                                   \
            aaH[n] = MFMA(aH, bwH, aaH[n]);                                   \
        }                                                                     \
    }                                                                         \
    _Pragma("unroll")                                                         \
    for (int j = 0; j < 4; ++j) {                                             \
        int row = kgrp * 4 + j;                                               \
        float a0 = tanhf_(aaL[0][j] + aaH[0][j]);                             \
        float a1 = tanhf_(aaL[1][j] + aaH[1][j]);                             \
        float h0 = __builtin_fmaf(az[0][j], a0 - h[0][j], h[0][j]);           \
        float h1 = __builtin_fmaf(az[1][j], a1 - h[1][j], h[1][j]);           \
        h[0][j] = h0; h[1][j] = h1;                                           \
        *(uint32_t*)(HBF + row * 512 + ((wid * 64 + lrow * 4) ^ ((row & 7) << 4))) = cvtpk_bf16(h0, h1); \
    }                                                                         \
    RAW_BARRIER();                                                            \
} while (0)

__global__ __launch_bounds__(THREADS, 2) void gru_rec(
    const int* __restrict__ x, const ushort* __restrict__ EG,
    const float* __restrict__ bp, const ushort* __restrict__ WhT,
    const ushort* __restrict__ WpT, float* __restrict__ out)
{
    char* WhA = smem + R_WHA;
    char* HBF = smem + R_HBF;
    char* RH  = smem + R_RH;
    int*  tokL = (int*)(smem + R_TOK);

    const int tid  = threadIdx.x;
    const int lane = tid & 63;
    const int wid  = tid >> 6;
    const int lrow = lane & 15;
    const int kgrp = lane >> 4;
    const int r0   = blockIdx.x * BM;
    const int ncol0 = wid * 32;
    const uint32_t* EGd = (const uint32_t*)EG;
    const int gcoff = (ncol0 >> 1) + lrow;     // dword offset within EG row

    // one-time LDS fill: Wh_a (rows K-permuted already), swizzled
    for (int c = tid; c < 8192; c += THREADS) {
        int row = c >> 5, ch = c & 31;
        short8 v = *(const short8*)&WhT[(size_t)(2 * HID + row) * HID + ch * 8];
        *(short8*)(WhA + row * 512 + ((ch * 16) ^ ((row & 7) << 4))) = v;
    }
    *(short8*)(HBF + tid * 16) = (short8){0,0,0,0,0,0,0,0};
    tokL[tid] = x[r0 * SEQ + tid];       // 16 rows x 32 steps

    // resident Wh z/r fragments (K-permuted), pinned against rematerialization
    short8 Wz[8][2], Wr[8][2];
    #pragma unroll
    for (int ks = 0; ks < 8; ++ks)
        #pragma unroll
        for (int n = 0; n < 2; ++n) {
            int colg = ncol0 + n * 16 + lrow;
            Wz[ks][n] = *(const short8*)&WhT[(size_t)colg * HID + ks * 32 + kgrp * 8];
            Wr[ks][n] = *(const short8*)&WhT[(size_t)(HID + colg) * HID + ks * 32 + kgrp * 8];
            asm volatile("" : "+v"(Wz[ks][n]), "+v"(Wr[ks][n]));
        }

    float bpr[2];
    #pragma unroll
    for (int n = 0; n < 2; ++n) bpr[n] = bp[ncol0 + n * 16 + lrow];

    float h[2][4] = {{0.f,0.f,0.f,0.f},{0.f,0.f,0.f,0.f}};

    __syncthreads();

    // prologue: gather EG pairs for t=0
    uint32_t gxA[12], gxB[12];
    #pragma unroll
    for (int j = 0; j < 4; ++j) {
        int tok = tokL[(kgrp * 4 + j) * SEQ + 0];
        const uint32_t* gp = EGd + (size_t)tok * 384 + gcoff;
        gxA[0 * 4 + j] = gp[0];
        gxA[1 * 4 + j] = gp[128];
        gxA[2 * 4 + j] = gp[256];
    }

    for (int t = 0; t < SEQ; t += 2) {
        GRU_STEP(t,     gxA, gxB);
        GRU_STEP(t + 1, gxB, gxA);
    }

    // ---- projection: out = h @ w_p + b_p (WpT K-permuted to match HBF slots) ----
    f32x4 ap[2] = {{0,0,0,0},{0,0,0,0}};
    #pragma unroll
    for (int ks = 0; ks < 8; ++ks) {
        short8 a = *(const short8*)(HBF + lrow * 512 + ((ks * 64 + kgrp * 16) ^ ((lrow & 7) << 4)));
        #pragma unroll
        for (int n = 0; n < 2; ++n) {
            int colg = ncol0 + n * 16 + lrow;
            short8 bw = *(const short8*)&WpT[(size_t)colg * HID + ks * 32 + kgrp * 8];
            ap[n] = MFMA(a, bw, ap[n]);
        }
    }
    #pragma unroll
    for (int n = 0; n < 2; ++n) {
        int colg = ncol0 + n * 16 + lrow;
        #pragma unroll
        for (int j = 0; j < 4; ++j) {
            int row = kgrp * 4 + j;
            out[(size_t)(r0 + row) * HID + colg] = ap[n][j] + bpr[n];
        }
    }
}

extern "C" void kernel_launch(void* const* d_in, const int* in_sizes, int n_in,
                              void* d_out, int out_size, void* d_ws, size_t ws_size,
                              hipStream_t stream) {
    const int*   x     = (const int*)d_in[0];
    const float* embed = (const float*)d_in[1];
    const float* wi    = (const float*)d_in[2];
    const float* wh    = (const float*)d_in[3];
    const float* b     = (const float*)d_in[4];
    const float* wp    = (const float*)d_in[5];
    const float* bp    = (const float*)d_in[6];
    float* out = (float*)d_out;
    ushort* ws = (ushort*)d_ws;

    (void)hipFuncSetAttribute((const void*)gru_rec,
                              hipFuncAttributeMaxDynamicSharedMemorySize, R_TOTAL);

    hipLaunchKernelGGL(prep_kernel, dim3((WS_WTOTAL + 255) / 256), dim3(256), 0, stream,
                       wi, wh, wp, ws);

    ushort* eg = ws + WS_EG;
    hipLaunchKernelGGL(eg_kernel, dim3(EGROWS / EGM), dim3(512), 0, stream,
                       embed, b, ws + WS_WIT, eg);
    hipLaunchKernelGGL(gru_rec, dim3(BATCH / BM), dim3(THREADS), R_TOTAL, stream,
                       x, eg, bp, ws + WS_WHT, ws + WS_WPT, out);
}

// Round 11
// 122.768 us; speedup vs baseline: 2.3835x; 1.0209x over previous
//
#include <hip/hip_runtime.h>
#include <stdint.h>

#define WDIM 128
#define HID 256
#define G3 768
#define VOCAB 50257
#define EGROWS 50304          // 393 * 128
#define BATCH 4096
#define SEQ 32
#define BM 16
#define THREADS 512

// ws layout (ushort units): WiT[768][128](gate-scaled), WhT[768][256](K-permuted, gate-scaled),
//                           WpT[256][256](K-permuted), EG[50304][768]
#define WS_WIT 0
#define WS_WHT 98304
#define WS_WPT 294912
#define WS_WTOTAL 360448
#define WS_EG  362496ULL      // byte offset 724992

// exp2 folding: z,r slices scaled by log2(e); a slice by 2*log2(e)
#define SC_ZR 1.44269504f
#define SC_A  2.88539008f

typedef __attribute__((ext_vector_type(8))) short short8;
typedef __attribute__((ext_vector_type(4))) float f32x4;

#define MFMA(a, b, c) __builtin_amdgcn_mfma_f32_16x16x32_bf16((a), (b), (c), 0, 0, 0)

__device__ __forceinline__ ushort f2bf(float f) {
    union { float f; uint32_t u; } v; v.f = f;
    uint32_t u = v.u;
    u += 0x7fffu + ((u >> 16) & 1u);   // RNE
    return (ushort)(u >> 16);
}
__device__ __forceinline__ float bf2f_lo(uint32_t p) {
    union { uint32_t u; float f; } v; v.u = p << 16; return v.f;
}
__device__ __forceinline__ float bf2f_hi(uint32_t p) {
    union { uint32_t u; float f; } v; v.u = p & 0xffff0000u; return v.f;
}
// exp2 via intrinsic: compiler handles the trans-op wait-state hazard (R10's raw asm
// v_exp_f32 hid the trans op from the hazard recognizer -> dependent VALU read stale reg).
__device__ __forceinline__ float exp2_(float x) {
#if __has_builtin(__builtin_amdgcn_exp2f)
    return __builtin_amdgcn_exp2f(x);
#else
    float e;
    asm volatile("v_exp_f32 %0, %1\n\ts_nop 1" : "=v"(e) : "v"(x));
    return e;
#endif
}
// sigmoid on pre-scaled input x' = log2(e)*x : 1/(1+2^(-x'))
__device__ __forceinline__ float sigmoid2_(float x) {
    return __builtin_amdgcn_rcpf(1.f + exp2_(-x));
}
// tanh on pre-scaled input x' = 2*log2(e)*x : 1 - 2/(2^x' + 1)
__device__ __forceinline__ float tanh2_(float x) {
    return __builtin_fmaf(-2.f, __builtin_amdgcn_rcpf(exp2_(x) + 1.f), 1.f);
}
__device__ __forceinline__ uint32_t cvtpk_bf16(float lo, float hi) {
    uint32_t pk;
    asm("v_cvt_pk_bf16_f32 %0, %1, %2" : "=v"(pk) : "v"(lo), "v"(hi));
    return pk;
}
// K-slot permutation: slot s holds original k = col_of_slot(s); pairs (c, c+16) adjacent.
__device__ __forceinline__ int col_of_slot(int s) {
    return (s & ~31) | ((s & 31) >> 1) | ((s & 1) << 4);
}

__global__ void prep_kernel(const float* __restrict__ wi, const float* __restrict__ wh,
                            const float* __restrict__ wp, ushort* __restrict__ ws) {
    int gid = blockIdx.x * blockDim.x + threadIdx.x;
    if (gid < G3 * WDIM) {
        int n = gid / WDIM, k = gid % WDIM;
        float sc = (n < 2 * HID) ? SC_ZR : SC_A;
        ws[WS_WIT + n * WDIM + k] = f2bf(wi[k * G3 + n] * sc);          // gate-scaled
    } else if (gid < G3 * WDIM + G3 * HID) {
        int g = gid - G3 * WDIM;
        int n = g / HID, s = g % HID;
        float sc = (n < 2 * HID) ? SC_ZR : SC_A;
        ws[WS_WHT + n * HID + s] = f2bf(wh[col_of_slot(s) * G3 + n] * sc); // K-permuted, scaled
    } else if (gid < G3 * WDIM + G3 * HID + HID * HID) {
        int g = gid - G3 * WDIM - G3 * HID;
        int n = g / HID, s = g % HID;
        ws[WS_WPT + n * HID + s] = f2bf(wp[col_of_slot(s) * HID + n]);  // K-permuted (unscaled)
    }
}

// ============ EG = bf16( embed @ Wi_scaled + b_scaled ) : M=50304, N=768, K=128 ============
// B-RESIDENT: 8 waves/block, wave w owns 96 cols (24 short8 = 96 VGPR, pinned).
#define EGM 128

__global__ __launch_bounds__(512, 2) void eg_kernel(
    const float* __restrict__ embed, const float* __restrict__ bias,
    const ushort* __restrict__ WiT, ushort* __restrict__ EG)
{
    __shared__ char At[32768];            // [128 rows][256B] bf16, XOR-swizzled
    const int tid  = threadIdx.x;
    const int lane = tid & 63, wid = tid >> 6;     // 8 waves
    const int lrow = lane & 15, kgrp = lane >> 4;
    const int m0  = blockIdx.x * EGM;
    const int c0  = wid * 96;                      // wave's col base

    {   // stage 128 embedding rows -> LDS bf16 (4 threads/row, 32 floats each)
        int row = tid >> 2, part = tid & 3;
        int er = m0 + row; if (er >= VOCAB) er = VOCAB - 1;
        const float* e = embed + (size_t)er * WDIM + part * 32;
        #pragma unroll
        for (int q = 0; q < 8; ++q) {
            float4 f = ((const float4*)e)[q];
            uint32_t p0 = f2bf(f.x) | ((uint32_t)f2bf(f.y) << 16);
            uint32_t p1 = f2bf(f.z) | ((uint32_t)f2bf(f.w) << 16);
            *(uint2*)(At + row * 256 + ((part * 64 + q * 8) ^ ((row & 7) << 4))) = (uint2){p0, p1};
        }
    }

    // B preload: 24 fragments, resident for the whole block
    short8 Bw[6][4];
    #pragma unroll
    for (int n = 0; n < 6; ++n)
        #pragma unroll
        for (int ks = 0; ks < 4; ++ks) {
            Bw[n][ks] = *(const short8*)&WiT[(size_t)(c0 + n * 16 + lrow) * WDIM + ks * 32 + kgrp * 8];
            asm volatile("" : "+v"(Bw[n][ks]));
        }

    float bv[6];
    #pragma unroll
    for (int n = 0; n < 6; ++n) {
        int colg = c0 + n * 16 + lrow;
        bv[n] = bias[colg] * ((colg < 2 * HID) ? SC_ZR : SC_A);
    }

    __syncthreads();

    #pragma unroll
    for (int rt = 0; rt < 8; ++rt) {
        const int arow = rt * 16 + lrow;
        short8 afr[4];
        #pragma unroll
        for (int ks = 0; ks < 4; ++ks)
            afr[ks] = *(const short8*)(At + arow * 256 + ((ks * 64 + kgrp * 16) ^ ((arow & 7) << 4)));

        f32x4 acc[6];
        #pragma unroll
        for (int n = 0; n < 6; ++n) acc[n] = (f32x4){0,0,0,0};
        #pragma unroll
        for (int ks = 0; ks < 4; ++ks)
            #pragma unroll
            for (int n = 0; n < 6; ++n)
                acc[n] = MFMA(afr[ks], Bw[n][ks], acc[n]);

        // pair-dword stores: cols (c0+32i+lrow, +16); 64B contiguous per 16 lanes
        #pragma unroll
        for (int i = 0; i < 3; ++i)
            #pragma unroll
            for (int j = 0; j < 4; ++j) {
                size_t m = (size_t)(m0 + rt * 16 + kgrp * 4 + j);
                *(uint32_t*)&EG[m * G3 + c0 + 32 * i + 2 * lrow] =
                    cvtpk_bf16(acc[2 * i][j] + bv[2 * i], acc[2 * i + 1][j] + bv[2 * i + 1]);
            }
    }
}

// ============ recurrent kernel (Wz/Wr regs, Wh_a LDS; raw barriers; exp2-folded) ============
#define R_WHA 0          // Wh_a (K-permuted rows) swizzled [256 cols][512B]  (128KB)
#define R_HBF 131072     // [16][512B] bf16 h, pair-slot layout, swizzled
#define R_RH  139264     // [16][512B] bf16 r*h, pair-slot layout, swizzled
#define R_TOK 147456     // [16][32] int token byte-offsets (2KB)
#define R_TOTAL 149504

extern __shared__ char smem[];

// raw barrier: flush LDS writes only; VMEM (EG prefetch) stays in flight
#define RAW_BARRIER() do {                                                    \
    asm volatile("s_waitcnt lgkmcnt(0)" ::: "memory");                        \
    __builtin_amdgcn_s_barrier();                                             \
    __builtin_amdgcn_sched_barrier(0);                                        \
} while (0)

// GC/GN: 12 dwords; [g*4+j] = pair (col ncol0+lrow | col ncol0+16+lrow) of gate g, row kgrp*4+j
#define GRU_STEP(T, GC, GN) do {                                              \
    int tn = ((T) + 1 < SEQ) ? (T) + 1 : SEQ - 1;                             \
    _Pragma("unroll")                                                         \
    for (int j = 0; j < 4; ++j) {                                             \
        int off = tokL[(kgrp * 4 + j) * SEQ + tn];                            \
        const uint32_t* gp = (const uint32_t*)(EGb + off) + gcoff;            \
        GN[0 * 4 + j] = gp[0];                                                \
        GN[1 * 4 + j] = gp[128];                                              \
        GN[2 * 4 + j] = gp[256];                                              \
    }                                                                         \
    f32x4 az[2], ar[2];                                                       \
    _Pragma("unroll")                                                         \
    for (int j = 0; j < 4; ++j) {                                             \
        az[0][j] = bf2f_lo(GC[0 * 4 + j]);                                    \
        az[1][j] = bf2f_hi(GC[0 * 4 + j]);                                    \
        ar[0][j] = bf2f_lo(GC[1 * 4 + j]);                                    \
        ar[1][j] = bf2f_hi(GC[1 * 4 + j]);                                    \
    }                                                                         \
    _Pragma("unroll")                                                         \
    for (int ks = 0; ks < 8; ++ks) {                                          \
        short8 a = *(const short8*)(HBF + lrow * 512 + ((ks * 64 + kgrp * 16) ^ ((lrow & 7) << 4))); \
        az[0] = MFMA(a, Wz[ks][0], az[0]);                                    \
        az[1] = MFMA(a, Wz[ks][1], az[1]);                                    \
        ar[0] = MFMA(a, Wr[ks][0], ar[0]);                                    \
        ar[1] = MFMA(a, Wr[ks][1], ar[1]);                                    \
    }                                                                         \
    _Pragma("unroll")                                                         \
    for (int j = 0; j < 4; ++j) {                                             \
        int row = kgrp * 4 + j;                                               \
        float z0 = sigmoid2_(az[0][j]); az[0][j] = z0;                        \
        float z1 = sigmoid2_(az[1][j]); az[1][j] = z1;                        \
        float r0 = sigmoid2_(ar[0][j]) * h[0][j];                             \
        float r1 = sigmoid2_(ar[1][j]) * h[1][j];                             \
        *(uint32_t*)(RH + row * 512 + ((wid * 64 + lrow * 4) ^ ((row & 7) << 4))) = cvtpk_bf16(r0, r1); \
    }                                                                         \
    RAW_BARRIER();                                                            \
    /* a-GEMM: 4 independent chains (2 cols x K-low/K-high) */                \
    f32x4 aaL[2], aaH[2];                                                     \
    _Pragma("unroll")                                                         \
    for (int j = 0; j < 4; ++j) {                                             \
        aaL[0][j] = bf2f_lo(GC[2 * 4 + j]);                                   \
        aaL[1][j] = bf2f_hi(GC[2 * 4 + j]);                                   \
        aaH[0][j] = 0.f; aaH[1][j] = 0.f;                                     \
    }                                                                         \
    _Pragma("unroll")                                                         \
    for (int ks = 0; ks < 4; ++ks) {                                          \
        short8 aL = *(const short8*)(RH + lrow * 512 + ((ks * 64 + kgrp * 16) ^ ((lrow & 7) << 4))); \
        short8 aH = *(const short8*)(RH + lrow * 512 + (((ks + 4) * 64 + kgrp * 16) ^ ((lrow & 7) << 4))); \
        _Pragma("unroll")                                                     \
        for (int n = 0; n < 2; ++n) {                                         \
            int colg = ncol0 + n * 16 + lrow;                                 \
            short8 bwL = *(const short8*)(WhA + colg * 512 + ((ks * 64 + kgrp * 16) ^ ((colg & 7) << 4))); \
            short8 bwH = *(const short8*)(WhA + colg * 512 + (((ks + 4) * 64 + kgrp * 16) ^ ((colg & 7) << 4))); \
            aaL[n] = MFMA(aL, bwL, aaL[n]);                                   \
            aaH[n] = MFMA(aH, bwH, aaH[n]);                                   \
        }                                                                     \
    }                                                                         \
    _Pragma("unroll")                                                         \
    for (int j = 0; j < 4; ++j) {                                             \
        int row = kgrp * 4 + j;                                               \
        float a0 = tanh2_(aaL[0][j] + aaH[0][j]);                             \
        float a1 = tanh2_(aaL[1][j] + aaH[1][j]);                             \
        float h0 = __builtin_fmaf(az[0][j], a0 - h[0][j], h[0][j]);           \
        float h1 = __builtin_fmaf(az[1][j], a1 - h[1][j], h[1][j]);           \
        h[0][j] = h0; h[1][j] = h1;                                           \
        *(uint32_t*)(HBF + row * 512 + ((wid * 64 + lrow * 4) ^ ((row & 7) << 4))) = cvtpk_bf16(h0, h1); \
    }                                                                         \
    RAW_BARRIER();                                                            \
} while (0)

__global__ __launch_bounds__(THREADS, 2) void gru_rec(
    const int* __restrict__ x, const ushort* __restrict__ EG,
    const float* __restrict__ bp, const ushort* __restrict__ WhT,
    const ushort* __restrict__ WpT, float* __restrict__ out)
{
    char* WhA = smem + R_WHA;
    char* HBF = smem + R_HBF;
    char* RH  = smem + R_RH;
    int*  tokL = (int*)(smem + R_TOK);

    const int tid  = threadIdx.x;
    const int lane = tid & 63;
    const int wid  = tid >> 6;
    const int lrow = lane & 15;
    const int kgrp = lane >> 4;
    const int r0   = blockIdx.x * BM;
    const int ncol0 = wid * 32;
    const char* EGb = (const char*)EG;
    const int gcoff = (ncol0 >> 1) + lrow;     // dword offset within EG row

    // one-time LDS fill: Wh_a (rows K-permuted already), swizzled
    for (int c = tid; c < 8192; c += THREADS) {
        int row = c >> 5, ch = c & 31;
        short8 v = *(const short8*)&WhT[(size_t)(2 * HID + row) * HID + ch * 8];
        *(short8*)(WhA + row * 512 + ((ch * 16) ^ ((row & 7) << 4))) = v;
    }
    *(short8*)(HBF + tid * 16) = (short8){0,0,0,0,0,0,0,0};
    tokL[tid] = x[r0 * SEQ + tid] * 1536;   // pre-multiplied byte offset into EG

    // resident Wh z/r fragments (K-permuted, scaled), pinned
    short8 Wz[8][2], Wr[8][2];
    #pragma unroll
    for (int ks = 0; ks < 8; ++ks)
        #pragma unroll
        for (int n = 0; n < 2; ++n) {
            int colg = ncol0 + n * 16 + lrow;
            Wz[ks][n] = *(const short8*)&WhT[(size_t)colg * HID + ks * 32 + kgrp * 8];
            Wr[ks][n] = *(const short8*)&WhT[(size_t)(HID + colg) * HID + ks * 32 + kgrp * 8];
            asm volatile("" : "+v"(Wz[ks][n]), "+v"(Wr[ks][n]));
        }

    float bpr[2];
    #pragma unroll
    for (int n = 0; n < 2; ++n) bpr[n] = bp[ncol0 + n * 16 + lrow];

    float h[2][4] = {{0.f,0.f,0.f,0.f},{0.f,0.f,0.f,0.f}};

    __syncthreads();

    // prologue: gather EG pairs for t=0
    uint32_t gxA[12], gxB[12];
    #pragma unroll
    for (int j = 0; j < 4; ++j) {
        int off = tokL[(kgrp * 4 + j) * SEQ + 0];
        const uint32_t* gp = (const uint32_t*)(EGb + off) + gcoff;
        gxA[0 * 4 + j] = gp[0];
        gxA[1 * 4 + j] = gp[128];
        gxA[2 * 4 + j] = gp[256];
    }

    for (int t = 0; t < SEQ; t += 2) {
        GRU_STEP(t,     gxA, gxB);
        GRU_STEP(t + 1, gxB, gxA);
    }

    // ---- projection: out = h @ w_p + b_p (WpT K-permuted to match HBF slots) ----
    f32x4 ap[2] = {{0,0,0,0},{0,0,0,0}};
    #pragma unroll
    for (int ks = 0; ks < 8; ++ks) {
        short8 a = *(const short8*)(HBF + lrow * 512 + ((ks * 64 + kgrp * 16) ^ ((lrow & 7) << 4)));
        #pragma unroll
        for (int n = 0; n < 2; ++n) {
            int colg = ncol0 + n * 16 + lrow;
            short8 bw = *(const short8*)&WpT[(size_t)colg * HID + ks * 32 + kgrp * 8];
            ap[n] = MFMA(a, bw, ap[n]);
        }
    }
    #pragma unroll
    for (int n = 0; n < 2; ++n) {
        int colg = ncol0 + n * 16 + lrow;
        #pragma unroll
        for (int j = 0; j < 4; ++j) {
            int row = kgrp * 4 + j;
            out[(size_t)(r0 + row) * HID + colg] = ap[n][j] + bpr[n];
        }
    }
}

extern "C" void kernel_launch(void* const* d_in, const int* in_sizes, int n_in,
                              void* d_out, int out_size, void* d_ws, size_t ws_size,
                              hipStream_t stream) {
    const int*   x     = (const int*)d_in[0];
    const float* embed = (const float*)d_in[1];
    const float* wi    = (const float*)d_in[2];
    const float* wh    = (const float*)d_in[3];
    const float* b     = (const float*)d_in[4];
    const float* wp    = (const float*)d_in[5];
    const float* bp    = (const float*)d_in[6];
    float* out = (float*)d_out;
    ushort* ws = (ushort*)d_ws;

    (void)hipFuncSetAttribute((const void*)gru_rec,
                              hipFuncAttributeMaxDynamicSharedMemorySize, R_TOTAL);

    hipLaunchKernelGGL(prep_kernel, dim3((WS_WTOTAL + 255) / 256), dim3(256), 0, stream,
                       wi, wh, wp, ws);

    ushort* eg = ws + WS_EG;
    hipLaunchKernelGGL(eg_kernel, dim3(EGROWS / EGM), dim3(512), 0, stream,
                       embed, b, ws + WS_WIT, eg);
    hipLaunchKernelGGL(gru_rec, dim3(BATCH / BM), dim3(THREADS), R_TOTAL, stream,
                       x, eg, bp, ws + WS_WHT, ws + WS_WPT, out);
}